// Round 4
// baseline (279.633 us; speedup 1.0000x reference)
//
#include <hip/hip_runtime.h>
#include <hip/hip_bf16.h>

typedef __bf16 bf16_t;
typedef __bf16 bf16x8 __attribute__((ext_vector_type(8)));
typedef float f32x4 __attribute__((ext_vector_type(4)));

#define B_ 8
#define LQ_ 2048
#define LK_ 2048
#define DM_ 1024

__device__ __forceinline__ void gload16(const void* g, void* l) {
  __builtin_amdgcn_global_load_lds(
      (const __attribute__((address_space(1))) void*)g,
      (__attribute__((address_space(3))) void*)l, 16, 0, 0);
}

// ---------------- f32 -> bf16 convert (vectorized) ----------------
__global__ __launch_bounds__(256) void cvt_bf16_kernel(
    const float* __restrict__ in, bf16_t* __restrict__ out, int n8) {
  int stride = gridDim.x * blockDim.x;
  for (int i = blockIdx.x * blockDim.x + threadIdx.x; i < n8; i += stride) {
    const float4* p = reinterpret_cast<const float4*>(in) + (size_t)i * 2;
    float4 a = p[0], b = p[1];
    bf16x8 o;
    o[0] = (bf16_t)a.x; o[1] = (bf16_t)a.y; o[2] = (bf16_t)a.z; o[3] = (bf16_t)a.w;
    o[4] = (bf16_t)b.x; o[5] = (bf16_t)b.y; o[6] = (bf16_t)b.z; o[7] = (bf16_t)b.w;
    *reinterpret_cast<bf16x8*>(out + (size_t)i * 8) = o;
  }
}

// ---------------- V [B][LK][DM] f32 -> Vt [B][DM][LK] bf16 ----------------
__global__ __launch_bounds__(256) void transpose_v(
    const float* __restrict__ V, bf16_t* __restrict__ Vt) {
  __shared__ bf16_t tile[64][65];
  int b = blockIdx.z;
  int k0 = blockIdx.x * 64;
  int d0 = blockIdx.y * 64;
  int r = threadIdx.x >> 6;
  int c = threadIdx.x & 63;
  const float* src = V + ((size_t)b * LK_ + k0) * DM_ + d0;
#pragma unroll
  for (int i = 0; i < 64; i += 4)
    tile[r + i][c] = (bf16_t)src[(size_t)(r + i) * DM_ + c];
  __syncthreads();
  bf16_t* dst = Vt + ((size_t)b * DM_ + d0) * LK_ + k0;
#pragma unroll
  for (int i = 0; i < 64; i += 4)
    dst[(size_t)(r + i) * LK_ + c] = tile[c][r + i];
}

// ---------------- 128x128 read-ahead pipelined GEMM, C = A * B^T ----------
// A: [M][K] bf16 row-major, B: [N][K] bf16 row-major.
// 4 waves (2Mx2N), wave tile 64x64, BK=64, 2 LDS K-tile dbufs (64 KiB total
// -> 2 blocks/CU). 8 phases per iteration (2 K-tiles). Each phase:
//   [ds_reads for NEXT phase's MFMA | stage | (vmcnt) | BAR | 8 MFMA]
// so the LDS pipe drains while the MFMA pipe runs (intra-wave read-ahead),
// and the sibling block on the CU fills whichever pipe this block leaves idle.
// K-slot swizzle (involution): phys_slot = slot ^ ((row>>1)&7), 8x16B slots.
// MODE 0: C bf16, C += bias[col]; MODE 1: C bf16, *(1/32)+mask; MODE 2: C f32.
#define BARX __builtin_amdgcn_s_barrier()
#define PRIO1 __builtin_amdgcn_s_setprio(1)
#define PRIO0 __builtin_amdgcn_s_setprio(0)
#define SCHED0 __builtin_amdgcn_sched_barrier(0)
#define VM0 asm volatile("s_waitcnt vmcnt(0)" ::: "memory")

#define RD_M(DST, MB, DOFF)                                                   \
  _Pragma("unroll") for (int m = 0; m < 2; ++m) {                             \
    DST[m][0] = *(const bf16x8*)(pa0 + (DOFF) + ((MB) + m) * 2048);           \
    DST[m][1] = *(const bf16x8*)(pa1 + (DOFF) + ((MB) + m) * 2048);           \
  }
#define RD_N(DST, NB, DOFF)                                                   \
  _Pragma("unroll") for (int n = 0; n < 2; ++n) {                             \
    DST[n][0] = *(const bf16x8*)(pb0 + (DOFF) + ((NB) + n) * 2048);           \
    DST[n][1] = *(const bf16x8*)(pb1 + (DOFF) + ((NB) + n) * 2048);           \
  }
#define MQ(MB, NB, MF, NF)                                                    \
  _Pragma("unroll") for (int m = 0; m < 2; ++m)                               \
  _Pragma("unroll") for (int n = 0; n < 2; ++n) {                             \
    acc[(MB) + m][(NB) + n] = __builtin_amdgcn_mfma_f32_16x16x32_bf16(        \
        MF[m][0], NF[n][0], acc[(MB) + m][(NB) + n], 0, 0, 0);                \
    acc[(MB) + m][(NB) + n] = __builtin_amdgcn_mfma_f32_16x16x32_bf16(        \
        MF[m][1], NF[n][1], acc[(MB) + m][(NB) + n], 0, 0, 0);                \
  }

template <int MODE>
__global__ __launch_bounds__(256, 2) void gemm_bt(
    const bf16_t* __restrict__ A, const bf16_t* __restrict__ Bm,
    void* __restrict__ Cv, const float* __restrict__ extra,
    int N, int K, long sA, long sB, long sC, long sE, int gxs, int gys) {
  __shared__ bf16_t lds[32768];  // 64 KiB: A [0,32KB) = d0,d1; B [32KB,64KB)

  const int tid = threadIdx.x;
  const int lane = tid & 63;
  const int wave = tid >> 6;

  // XCD-aware bijective block swizzle (gridDim.x % 8 == 0 for all our grids)
  const int nwg = gridDim.x;
  const int lin = blockIdx.x;
  const int cpx = nwg >> 3;
  const int swz = (lin & 7) * cpx + (lin >> 3);
  const int gx = 1 << gxs;
  const int bx = swz & (gx - 1);
  const int rem = swz >> gxs;
  const int by = rem & ((1 << gys) - 1);
  const int bz = rem >> gys;

  const bf16_t* Ab = A + (long)bz * sA + (long)(by * 128) * K;
  const bf16_t* Bb = Bm + (long)bz * sB + (long)(bx * 128) * K;

  // staging: 256 threads cover 32 rows x 64 cols per gload group; 4 groups.
  const int r0 = tid >> 3;                              // 0..31
  const int scol = ((tid & 7) ^ ((r0 >> 1) & 7)) * 8;   // pre-swizzled col

  auto STG = [&](const bf16_t* Mb, int mat, int d, int t) {
    const bf16_t* g = Mb + (long)r0 * K + t * 64 + scol;
    bf16_t* l = lds + mat * 16384 + d * 8192 + wave * 512;
#pragma unroll
    for (int kq = 0; kq < 4; ++kq)
      gload16(g + (long)(kq * 32) * K, l + kq * 2048);
  };

  // fragment read geometry
  const int wr = wave >> 1;   // 0..1
  const int wc = wave & 1;    // 0..1
  const int fr = lane & 15;
  const int g = lane >> 4;
  const int q5 = (fr >> 1) & 7;
  const int sb0 = (g ^ q5) * 16;         // kk=0 slot bytes (phys)
  const int sb1 = ((4 + g) ^ q5) * 16;   // kk=1
  const char* ldsc = (const char*)lds;
  const char* pa0 = ldsc + (wr * 64 + fr) * 128 + sb0;
  const char* pa1 = ldsc + (wr * 64 + fr) * 128 + sb1;
  const char* pb0 = ldsc + 32768 + (wc * 64 + fr) * 128 + sb0;
  const char* pb1 = ldsc + 32768 + (wc * 64 + fr) * 128 + sb1;

  f32x4 acc[4][4] = {};
  bf16x8 M01[2][2], M23[2][2], N01A[2][2], N01B[2][2], N23[2][2];

  const int NT2 = K >> 7;  // iterations, 2 K-tiles (BK=64) each; >= 2 here

  // prologue: tile0 -> dbuf0, tile1 -> dbuf1
  STG(Ab, 0, 0, 0); STG(Bb, 1, 0, 0);
  STG(Ab, 0, 1, 1); STG(Bb, 1, 1, 1);
  asm volatile("s_waitcnt vmcnt(8)" ::: "memory");  // tile0 landed
  BARX; SCHED0;
  RD_M(M01, 0, 0); RD_N(N01A, 0, 0);

  for (int j = 0; j < NT2; ++j) {
    const bool nl = (j + 1 < NT2);
    // P0: MFMA (m01,n01)(a) | reads N23(a) | stage A(d=2j+1)
    RD_N(N23, 2, 0);
    if (j > 0) STG(Ab, 0, 1, 2 * j + 1);
    BARX; PRIO1; MQ(0, 0, M01, N01A); PRIO0;
    // P1: (m01,n23)(a) | reads M23(a) | stage B(d)
    RD_M(M23, 2, 0);
    if (j > 0) STG(Bb, 1, 1, 2 * j + 1);
    BARX; PRIO1; MQ(0, 2, M01, N23); PRIO0;
    // P2: (m23,n23)(a) | drain dbuf1 loads
    VM0;
    BARX; SCHED0; PRIO1; MQ(2, 2, M23, N23); PRIO0;
    // P3: (m23,n01)(a) | reads M01(b), N01B(b) from dbuf1
    RD_M(M01, 0, 16384); RD_N(N01B, 0, 16384);
    BARX; PRIO1; MQ(2, 0, M23, N01A); PRIO0;
    // P4: (m01,n01)(b) | reads N23(b) | stage A(c=2j+2)
    RD_N(N23, 2, 16384);
    if (nl) STG(Ab, 0, 0, 2 * j + 2);
    BARX; PRIO1; MQ(0, 0, M01, N01B); PRIO0;
    // P5: (m01,n23)(b) | reads M23(b) | stage B(c)
    RD_M(M23, 2, 16384);
    if (nl) STG(Bb, 1, 0, 2 * j + 2);
    BARX; PRIO1; MQ(0, 2, M01, N23); PRIO0;
    // P6: (m23,n23)(b) | drain dbuf0 loads
    if (nl) { VM0; }
    BARX; SCHED0; PRIO1; MQ(2, 2, M23, N23); PRIO0;
    // P7: (m23,n01)(b) | reads M01(c), N01A(c) from refreshed dbuf0
    if (nl) { RD_M(M01, 0, 0); RD_N(N01A, 0, 0); }
    BARX; PRIO1; MQ(2, 0, M23, N01B); PRIO0;
  }

  // epilogue
  const int cn = lane & 15;
  const int rr = (lane >> 4) * 4;
  const int row0 = by * 128 + wr * 64;
  const int col0 = bx * 128 + wc * 64;
#pragma unroll
  for (int m = 0; m < 4; ++m) {
    const int row = row0 + m * 16 + rr;
#pragma unroll
    for (int n = 0; n < 4; ++n) {
      const int col = col0 + n * 16 + cn;
      if (MODE == 0) {
        bf16_t* C = (bf16_t*)Cv;
        float bias = extra[col];
#pragma unroll
        for (int j = 0; j < 4; ++j)
          C[(long)(row + j) * N + col] = (bf16_t)(acc[m][n][j] + bias);
      } else if (MODE == 1) {
        bf16_t* C = (bf16_t*)Cv + (long)bz * sC;
        float mk = extra[(long)bz * sE + col];
#pragma unroll
        for (int j = 0; j < 4; ++j)
          C[(long)(row + j) * N + col] = (bf16_t)(acc[m][n][j] * 0.03125f + mk);
      } else {
        float* C = (float*)Cv + (long)bz * sC;
#pragma unroll
        for (int j = 0; j < 4; ++j)
          C[(long)(row + j) * N + col] = acc[m][n][j];
      }
    }
  }
}

// ---------------- row softmax, in-place on bf16 logits ----------------
__global__ __launch_bounds__(256) void softmax_rows(bf16_t* __restrict__ logits) {
  long row = blockIdx.x;
  bf16_t* p = logits + row * LK_;
  int t = threadIdx.x;
  int lane = t & 63, wave = t >> 6;
  bf16x8 v = *reinterpret_cast<const bf16x8*>(p + t * 8);
  float f[8];
  float mx = -3e38f;
#pragma unroll
  for (int j = 0; j < 8; ++j) {
    f[j] = (float)v[j];
    mx = fmaxf(mx, f[j]);
  }
#pragma unroll
  for (int off = 32; off > 0; off >>= 1) mx = fmaxf(mx, __shfl_xor(mx, off, 64));
  __shared__ float red[8];
  if (lane == 0) red[wave] = mx;
  __syncthreads();
  mx = fmaxf(fmaxf(red[0], red[1]), fmaxf(red[2], red[3]));
  float s = 0.f;
#pragma unroll
  for (int j = 0; j < 8; ++j) {
    f[j] = __expf(f[j] - mx);
    s += f[j];
  }
#pragma unroll
  for (int off = 32; off > 0; off >>= 1) s += __shfl_xor(s, off, 64);
  if (lane == 0) red[4 + wave] = s;
  __syncthreads();
  s = red[4] + red[5] + red[6] + red[7];
  float inv = 1.f / s;
#pragma unroll
  for (int j = 0; j < 8; ++j) v[j] = (bf16_t)(f[j] * inv);
  *reinterpret_cast<bf16x8*>(p + t * 8) = v;
}

extern "C" void kernel_launch(void* const* d_in, const int* in_sizes, int n_in,
                              void* d_out, int out_size, void* d_ws, size_t ws_size,
                              hipStream_t stream) {
  const float* x    = (const float*)d_in[0];
  const float* mask = (const float*)d_in[1];
  const float* keys = (const float*)d_in[2];
  const float* vals = (const float*)d_in[3];
  const float* Wq   = (const float*)d_in[4];
  const float* bq   = (const float*)d_in[5];
  float* out = (float*)d_out;

  char* ws = (char*)d_ws;
  bf16_t* kbf    = (bf16_t*)(ws);
  bf16_t* vt     = (bf16_t*)(ws + 33554432);
  bf16_t* qbf    = (bf16_t*)(ws + 67108864);
  bf16_t* logits = (bf16_t*)(ws + 100663296);
  bf16_t* xbf    = logits;  // reused: x_bf dead before logits are written
  bf16_t* wqbf   = (bf16_t*)(ws + 167772160);

  // 1. converts
  cvt_bf16_kernel<<<2048, 256, 0, stream>>>(x, xbf, (B_ * LQ_ * DM_) / 8);
  cvt_bf16_kernel<<<2048, 256, 0, stream>>>(keys, kbf, (B_ * LK_ * DM_) / 8);
  cvt_bf16_kernel<<<256, 256, 0, stream>>>(Wq, wqbf, (DM_ * DM_) / 8);
  transpose_v<<<dim3(LK_ / 64, DM_ / 64, B_), 256, 0, stream>>>(vals, vt);

  // 2. Q = x @ Wq^T + bq   (M=16384, N=1024, K=1024) grid 8x128 = 1024
  gemm_bt<0><<<1024, 256, 0, stream>>>(
      xbf, wqbf, qbf, bq, DM_, DM_, 0, 0, 0, 0, 3, 7);

  // 3. logits = Q@K^T/32 + mask (per batch M=2048,N=2048,K=1024) 16x16x8 = 2048
  gemm_bt<1><<<2048, 256, 0, stream>>>(
      qbf, kbf, logits, mask, LK_, DM_,
      (long)LQ_ * DM_, (long)LK_ * DM_, (long)LQ_ * LK_, LK_, 4, 4);

  // 4. softmax rows, in place
  softmax_rows<<<B_ * LQ_, 256, 0, stream>>>(logits);

  // 5. out = P @ Vt^T   (per batch M=2048, N=1024, K=2048) 8x16x8 = 1024
  gemm_bt<2><<<1024, 256, 0, stream>>>(
      logits, vt, out, nullptr, DM_, LK_,
      (long)LQ_ * LK_, (long)DM_ * LK_, (long)LQ_ * DM_, 0, 3, 4);
}